// Round 1
// baseline (700.269 us; speedup 1.0000x reference)
//
#include <hip/hip_runtime.h>

#define NROWS 16384
#define DIM 64
#define BQ 64
#define BK 64
#define LDE 88                 // padded LDS row stride (elements): 176B = 16B-aligned, 2-way banks
#define NTILES (NROWS / BK)

typedef __attribute__((ext_vector_type(8))) __bf16 bf16x8;
typedef __attribute__((ext_vector_type(8))) short short8;
typedef __attribute__((ext_vector_type(4))) float f32x4;

static __device__ __forceinline__ unsigned short f2bf(float x) {
  unsigned u = __builtin_bit_cast(unsigned, x);
  u = (u + 0x7fffu + ((u >> 16) & 1u)) >> 16;   // RNE, inputs are normal floats
  return (unsigned short)u;
}
static __device__ __forceinline__ float bf2f(unsigned short b) {
  return __builtin_bit_cast(float, ((unsigned)b) << 16);
}

static __device__ __forceinline__ f32x4 mfma_bf16(short8 a, short8 b, f32x4 c) {
  return __builtin_amdgcn_mfma_f32_16x16x32_bf16(
      __builtin_bit_cast(bf16x8, a), __builtin_bit_cast(bf16x8, b), c, 0, 0, 0);
}

__global__ __launch_bounds__(256)
void grad_attn_kernel(const float* __restrict__ p, float* __restrict__ out) {
  __shared__ __align__(16) unsigned short sKhi[BK][LDE];
  __shared__ __align__(16) unsigned short sKlo[BK][LDE];
  __shared__ __align__(16) unsigned short sVt[DIM][LDE];
  __shared__ __align__(16) unsigned short sP[4][16][LDE];

  const int t  = threadIdx.x;
  const int w  = t >> 6;         // wave id (0..3)
  const int l  = t & 63;         // lane
  const int lr = l & 15;         // fragment row/col index
  const int lg = l >> 4;         // k-group (0..3)

  const int q0 = blockIdx.x * BQ + w * 16;

  // ---- Q fragments (hi/lo split). A-layout: row = lr, k = lg*8 + i (+32*kc)
  short8 qhi[2], qlo[2];
#pragma unroll
  for (int kc = 0; kc < 2; ++kc) {
    const float* qp = p + (size_t)(q0 + lr) * DIM + kc * 32 + lg * 8;
    float4 fa = *(const float4*)qp;
    float4 fb = *(const float4*)(qp + 4);
    float v[8] = {fa.x, fa.y, fa.z, fa.w, fb.x, fb.y, fb.z, fb.w};
    short8 h, lo2;
#pragma unroll
    for (int i = 0; i < 8; ++i) {
      unsigned short hb = f2bf(v[i]);
      h[i]   = (short)hb;
      lo2[i] = (short)f2bf(v[i] - bf2f(hb));
    }
    qhi[kc] = h;
    qlo[kc] = lo2;
  }

  const f32x4 z4 = {0.f, 0.f, 0.f, 0.f};
  f32x4 oacc[4] = {z4, z4, z4, z4};
  float mrun[4] = {-1e30f, -1e30f, -1e30f, -1e30f};
  float lrun[4] = {0.f, 0.f, 0.f, 0.f};

  // staging assignment: each thread: 2 rows x 8 cols
  const int srow = (t >> 3) * 2;        // 0..62 (even)
  const int sc0  = (t & 7) * 8;
  const int scs  = sc0 ^ (((srow >> 3) & 7) << 3);  // swizzled col base (same for srow+1)

  const float S2 = -4.0f * 1.4426950408889634f;  // log2-domain score scale

  for (int kt = 0; kt < NTILES; ++kt) {
    const int kv0 = kt * BK;
    __syncthreads();
    // ---- stage K(hi), K(lo), V^T(hi) for this KV tile
    {
      const float* s0 = p + (size_t)(kv0 + srow) * DIM + sc0;
      float4 a0 = *(const float4*)s0;
      float4 b0 = *(const float4*)(s0 + 4);
      float4 a1 = *(const float4*)(s0 + DIM);
      float4 b1 = *(const float4*)(s0 + DIM + 4);
      float v0[8] = {a0.x, a0.y, a0.z, a0.w, b0.x, b0.y, b0.z, b0.w};
      float v1[8] = {a1.x, a1.y, a1.z, a1.w, b1.x, b1.y, b1.z, b1.w};
      short8 h0, h1, l0, l1;
#pragma unroll
      for (int i = 0; i < 8; ++i) {
        unsigned short hb0 = f2bf(v0[i]);
        unsigned short hb1 = f2bf(v1[i]);
        h0[i] = (short)hb0; l0[i] = (short)f2bf(v0[i] - bf2f(hb0));
        h1[i] = (short)hb1; l1[i] = (short)f2bf(v1[i] - bf2f(hb1));
      }
      *(short8*)&sKhi[srow][scs]     = h0;
      *(short8*)&sKlo[srow][scs]     = l0;
      *(short8*)&sKhi[srow + 1][scs] = h1;
      *(short8*)&sKlo[srow + 1][scs] = l1;
#pragma unroll
      for (int i = 0; i < 8; ++i) {
        int d = sc0 + i;
        unsigned pk = (unsigned)(unsigned short)h0[i] |
                      (((unsigned)(unsigned short)h1[i]) << 16);
        *(unsigned*)&sVt[d][srow ^ (((d >> 3) & 7) << 3)] = pk;
      }
    }
    __syncthreads();

    // ---- QK^T: 16 q-rows x 64 kv, hi/lo error-compensated (3 MFMA per chunk)
    f32x4 acc[4] = {z4, z4, z4, z4};
#pragma unroll
    for (int c = 0; c < 4; ++c) {
      const int krow = c * 16 + lr;
      const int swc  = ((krow >> 3) & 7) << 3;
#pragma unroll
      for (int kc = 0; kc < 2; ++kc) {
        const int off = (kc * 32 + lg * 8) ^ swc;
        short8 bh = *(const short8*)&sKhi[krow][off];
        short8 bl = *(const short8*)&sKlo[krow][off];
        acc[c] = mfma_bf16(qhi[kc], bh, acc[c]);
        acc[c] = mfma_bf16(qhi[kc], bl, acc[c]);
        acc[c] = mfma_bf16(qlo[kc], bh, acc[c]);
      }
    }

    // ---- online softmax in log2 domain; C-layout: col=lane&15, row=(lane>>4)*4+r
    float P[4][4];
#pragma unroll
    for (int r = 0; r < 4; ++r) {
      float e0 = acc[0][r] * S2;
      float e1 = acc[1][r] * S2;
      float e2 = acc[2][r] * S2;
      float e3 = acc[3][r] * S2;
      float mt = fmaxf(fmaxf(e0, e1), fmaxf(e2, e3));
      mt = fmaxf(mt, __shfl_xor(mt, 1));
      mt = fmaxf(mt, __shfl_xor(mt, 2));
      mt = fmaxf(mt, __shfl_xor(mt, 4));
      mt = fmaxf(mt, __shfl_xor(mt, 8));
      const float mn = fmaxf(mrun[r], mt);
      const float sc = exp2f(mrun[r] - mn);
      mrun[r] = mn;
      float p0 = exp2f(e0 - mn);
      float p1 = exp2f(e1 - mn);
      float p2 = exp2f(e2 - mn);
      float p3 = exp2f(e3 - mn);
      P[0][r] = p0; P[1][r] = p1; P[2][r] = p2; P[3][r] = p3;
      float ps = (p0 + p1) + (p2 + p3);
      ps += __shfl_xor(ps, 1);
      ps += __shfl_xor(ps, 2);
      ps += __shfl_xor(ps, 4);
      ps += __shfl_xor(ps, 8);
      lrun[r] = lrun[r] * sc + ps;
#pragma unroll
      for (int dc = 0; dc < 4; ++dc) oacc[dc][r] *= sc;
    }

    // ---- P -> per-wave LDS staging (C-layout scatter -> A-layout reads)
    {
      const int irow = lg * 4;
      const int swp  = ((l >> 5) & 1) << 3;   // ((irow+r)>>3)&7, constant per lane
#pragma unroll
      for (int c = 0; c < 4; ++c) {
        const int colb = (c * 16 + lr) ^ swp;
#pragma unroll
        for (int r = 0; r < 4; ++r)
          sP[w][irow + r][colb] = f2bf(P[c][r]);
      }
    }

    // ---- PV: oacc[dc] += P[16x32] * V[32x16]  (per-wave LDS, no barrier needed)
#pragma unroll
    for (int kc = 0; kc < 2; ++kc) {
      const int kb = kc * 32 + lg * 8;
      short8 pa = *(const short8*)&sP[w][lr][kb ^ (((lr >> 3) & 1) << 3)];
#pragma unroll
      for (int dc = 0; dc < 4; ++dc) {
        const int d = dc * 16 + lr;
        short8 vb = *(const short8*)&sVt[d][kb ^ (((d >> 3) & 7) << 3)];
        oacc[dc] = mfma_bf16(pa, vb, oacc[dc]);
      }
    }
  }

  // ---- epilogue: out = p + ALPHA*(o/l - p)
#pragma unroll
  for (int r = 0; r < 4; ++r) {
    const float inv  = 1.0f / lrun[r];
    const size_t grow = (size_t)(q0 + lg * 4 + r) * DIM;
#pragma unroll
    for (int dc = 0; dc < 4; ++dc) {
      const int col = dc * 16 + lr;
      const float pv = p[grow + col];
      const float o  = oacc[dc][r] * inv;
      out[grow + col] = pv + 0.1f * (o - pv);
    }
  }
}

extern "C" void kernel_launch(void* const* d_in, const int* in_sizes, int n_in,
                              void* d_out, int out_size, void* d_ws, size_t ws_size,
                              hipStream_t stream) {
  const float* p = (const float*)d_in[0];
  float* out = (float*)d_out;
  grad_attn_kernel<<<dim3(NROWS / BQ), dim3(256), 0, stream>>>(p, out);
}

// Round 2
// 330.973 us; speedup vs baseline: 2.1158x; 2.1158x over previous
//
#include <hip/hip_runtime.h>
#include <stdint.h>

#define NROWS 16384
#define DIM 64
#define BK 64
#define NT (NROWS / BK)        // 256 KV tiles
#define NQT (NROWS / 64)       // 256 Q tiles
#define TILE_BYTES 24576       // Khi(8K) + Klo(8K) + Vt(8K), swizzled
#define KHI_OFF 0
#define KLO_OFF 8192
#define VT_OFF 16384

typedef __attribute__((ext_vector_type(8))) __bf16 bf16x8;
typedef __attribute__((ext_vector_type(8))) short short8;
typedef __attribute__((ext_vector_type(8))) unsigned short ushort8;
typedef __attribute__((ext_vector_type(4))) float f32x4;

#define WAITVM0 asm volatile("s_waitcnt vmcnt(0)" ::: "memory")

static __device__ __forceinline__ unsigned short f2bf(float x) {
  unsigned u = __builtin_bit_cast(unsigned, x);
  u = (u + 0x7fffu + ((u >> 16) & 1u)) >> 16;   // RNE
  return (unsigned short)u;
}
static __device__ __forceinline__ float bf2f(unsigned short b) {
  return __builtin_bit_cast(float, ((unsigned)b) << 16);
}
static __device__ __forceinline__ f32x4 mfma_bf16(short8 a, short8 b, f32x4 c) {
  return __builtin_amdgcn_mfma_f32_16x16x32_bf16(
      __builtin_bit_cast(bf16x8, a), __builtin_bit_cast(bf16x8, b), c, 0, 0, 0);
}
static __device__ __forceinline__ void gload_lds16(const void* g, void* l) {
  __builtin_amdgcn_global_load_lds(
      (const __attribute__((address_space(1))) unsigned int*)(uintptr_t)g,
      (__attribute__((address_space(3))) unsigned int*)(unsigned int)(uintptr_t)l,
      16, 0, 0);
}

// ---------------- prologue: pack p -> swizzled bf16 tiles (Khi/Klo/Vt) -------
__global__ __launch_bounds__(256)
void pack_kernel(const float* __restrict__ p, unsigned char* __restrict__ tiles) {
  __shared__ unsigned short sT[64][72];
  const int kt = blockIdx.x;
  const int t  = threadIdx.x;
  const int r  = t >> 2;
  const int q  = t & 3;
  const int k0 = q * 16;

  const float* src = p + ((size_t)(kt * 64 + r)) * DIM + k0;
  float4 f0 = ((const float4*)src)[0];
  float4 f1 = ((const float4*)src)[1];
  float4 f2 = ((const float4*)src)[2];
  float4 f3 = ((const float4*)src)[3];
  float v[16] = {f0.x, f0.y, f0.z, f0.w, f1.x, f1.y, f1.z, f1.w,
                 f2.x, f2.y, f2.z, f2.w, f3.x, f3.y, f3.z, f3.w};
  ushort8 h0, h1, l0, l1;
#pragma unroll
  for (int i = 0; i < 8; ++i) {
    unsigned short a = f2bf(v[i]);
    unsigned short b = f2bf(v[8 + i]);
    h0[i] = a; l0[i] = f2bf(v[i] - bf2f(a));
    h1[i] = b; l1[i] = f2bf(v[8 + i] - bf2f(b));
  }
  unsigned char* tb = tiles + (size_t)kt * TILE_BYTES;
  const int swz = (r & 7) << 4;
  const int b0  = r * 128 + ((2 * k0) ^ swz);
  const int b1  = r * 128 + ((2 * k0 + 16) ^ swz);
  *(ushort8*)(tb + KHI_OFF + b0) = h0;
  *(ushort8*)(tb + KHI_OFF + b1) = h1;
  *(ushort8*)(tb + KLO_OFF + b0) = l0;
  *(ushort8*)(tb + KLO_OFF + b1) = l1;

  // transpose hi through LDS for Vt
  *(ushort8*)&sT[r][k0]     = h0;
  *(ushort8*)&sT[r][k0 + 8] = h1;
  __syncthreads();
  const int d   = t >> 2;
  const int kv0 = q * 16;
  ushort8 a8, b8;
#pragma unroll
  for (int j = 0; j < 8; ++j) {
    a8[j] = sT[kv0 + j][d];
    b8[j] = sT[kv0 + 8 + j][d];
  }
  const int swzd = (d & 7) << 4;
  *(ushort8*)(tb + VT_OFF + d * 128 + ((2 * kv0) ^ swzd))      = a8;
  *(ushort8*)(tb + VT_OFF + d * 128 + ((2 * kv0 + 16) ^ swzd)) = b8;
}

// ---------------- main flash kernel (split-KV) -------------------------------
__global__ __launch_bounds__(256)
void attn_main(const float* __restrict__ p, const unsigned char* __restrict__ tiles,
               float* __restrict__ out, float* __restrict__ partO,
               float* __restrict__ partML, int S, int writeDirect) {
  __shared__ __align__(16) unsigned char sbuf[2][TILE_BYTES];
  __shared__ __align__(16) unsigned char sPb[4][2048];

  const int t  = threadIdx.x;
  const int w  = t >> 6;
  const int l  = t & 63;
  const int lr = l & 15;
  const int lg = l >> 4;
  const int qt = blockIdx.x;
  const int s  = blockIdx.y;
  const int ntp = NT / S;
  const int kt0 = s * ntp;

  // Q fragments straight from packed tiles (Q-tile == K-tile layout)
  const unsigned char* qtb = tiles + (size_t)qt * TILE_BYTES;
  const int rr   = w * 16 + lr;
  const int swzq = (rr & 7) << 4;
  short8 qhi[2], qlo[2];
#pragma unroll
  for (int kc = 0; kc < 2; ++kc) {
    const int off = rr * 128 + ((kc * 64 + lg * 16) ^ swzq);
    qhi[kc] = *(const short8*)(qtb + KHI_OFF + off);
    qlo[kc] = *(const short8*)(qtb + KLO_OFF + off);
  }

  const f32x4 z4 = {0.f, 0.f, 0.f, 0.f};
  f32x4 oacc[4] = {z4, z4, z4, z4};
  float mrun[4] = {-1e30f, -1e30f, -1e30f, -1e30f};
  float lrun[4] = {0.f, 0.f, 0.f, 0.f};
  const float S2 = -4.0f * 1.4426950408889634f;  // log2-domain score scale

  // stage tile kt into LDS buffer b (6 x 1KB wave-chunks per wave)
  auto STAGE = [&](int kt, int b) {
    const unsigned char* g = tiles + (size_t)kt * TILE_BYTES + (w * 6) * 1024 + l * 16;
    unsigned char* lb = &sbuf[b][(w * 6) * 1024];
#pragma unroll
    for (int c = 0; c < 6; ++c)
      gload_lds16(g + c * 1024, lb + c * 1024);
  };

  STAGE(kt0, 0);
  WAITVM0;
  __builtin_amdgcn_s_barrier();

  for (int i = 0; i < ntp; ++i) {
    if (i + 1 < ntp) STAGE(kt0 + i + 1, (i + 1) & 1);

    const unsigned char* kb = &sbuf[i & 1][0];

    // ---- QK^T (hi/lo compensated, 3 MFMA per 32-k chunk)
    f32x4 acc[4] = {z4, z4, z4, z4};
#pragma unroll
    for (int c = 0; c < 4; ++c) {
      const int krow = c * 16 + lr;
      const int swz  = (krow & 7) << 4;
#pragma unroll
      for (int kc = 0; kc < 2; ++kc) {
        const int off = krow * 128 + ((kc * 64 + lg * 16) ^ swz);
        short8 bh = *(const short8*)(kb + KHI_OFF + off);
        short8 bl = *(const short8*)(kb + KLO_OFF + off);
        acc[c] = mfma_bf16(qhi[kc], bh, acc[c]);
        acc[c] = mfma_bf16(qhi[kc], bl, acc[c]);
        acc[c] = mfma_bf16(qlo[kc], bh, acc[c]);
      }
    }

    // ---- online softmax (log2 domain); C-layout: col=lane&15, row=lg*4+r
    float P[4][4];
#pragma unroll
    for (int r2 = 0; r2 < 4; ++r2) {
      float e0 = acc[0][r2] * S2;
      float e1 = acc[1][r2] * S2;
      float e2 = acc[2][r2] * S2;
      float e3 = acc[3][r2] * S2;
      float mt = fmaxf(fmaxf(e0, e1), fmaxf(e2, e3));
      mt = fmaxf(mt, __shfl_xor(mt, 1));
      mt = fmaxf(mt, __shfl_xor(mt, 2));
      mt = fmaxf(mt, __shfl_xor(mt, 4));
      mt = fmaxf(mt, __shfl_xor(mt, 8));
      const float mn = fmaxf(mrun[r2], mt);
      const float sc = exp2f(mrun[r2] - mn);
      mrun[r2] = mn;
      float p0 = exp2f(e0 - mn);
      float p1 = exp2f(e1 - mn);
      float p2 = exp2f(e2 - mn);
      float p3 = exp2f(e3 - mn);
      P[0][r2] = p0; P[1][r2] = p1; P[2][r2] = p2; P[3][r2] = p3;
      float ps = (p0 + p1) + (p2 + p3);
      ps += __shfl_xor(ps, 1);
      ps += __shfl_xor(ps, 2);
      ps += __shfl_xor(ps, 4);
      ps += __shfl_xor(ps, 8);
      lrun[r2] = lrun[r2] * sc + ps;
#pragma unroll
      for (int dc = 0; dc < 4; ++dc) oacc[dc][r2] *= sc;
    }

    // ---- P -> per-wave LDS (C-layout scatter), swizzled
    unsigned char* pw = &sPb[w][0];
#pragma unroll
    for (int c = 0; c < 4; ++c) {
#pragma unroll
      for (int r2 = 0; r2 < 4; ++r2) {
        const int row = lg * 4 + r2;
        const int off = row * 128 + (((c * 16 + lr) * 2) ^ ((row & 7) << 4));
        *(unsigned short*)(pw + off) = f2bf(P[c][r2]);
      }
    }

    // ---- PV (same-wave LDS ordering, no barrier needed)
#pragma unroll
    for (int kc = 0; kc < 2; ++kc) {
      const int kbyte = kc * 64 + lg * 16;
      short8 pa = *(const short8*)(pw + lr * 128 + (kbyte ^ ((lr & 7) << 4)));
#pragma unroll
      for (int dc = 0; dc < 4; ++dc) {
        const int d = dc * 16 + lr;
        short8 vb = *(const short8*)(kb + VT_OFF + d * 128 + (kbyte ^ ((d & 7) << 4)));
        oacc[dc] = mfma_bf16(pa, vb, oacc[dc]);
      }
    }

    WAITVM0;                       // staged next tile landed (hid under compute)
    __builtin_amdgcn_s_barrier();  // everyone done with buf[i&1] + next tile ready
  }

  // ---- epilogue
  if (writeDirect) {
#pragma unroll
    for (int r2 = 0; r2 < 4; ++r2) {
      const float inv = 1.0f / lrun[r2];
      const size_t grow = (size_t)(qt * 64 + w * 16 + lg * 4 + r2) * DIM;
#pragma unroll
      for (int dc = 0; dc < 4; ++dc) {
        const int col = dc * 16 + lr;
        const float pv = p[grow + col];
        const float o  = oacc[dc][r2] * inv;
        out[grow + col] = pv + 0.1f * (o - pv);
      }
    }
  } else {
    float* po  = partO + (size_t)(qt * S + s) * 4096;
    float* pml = partML + (size_t)(qt * S + s) * 128;
#pragma unroll
    for (int r2 = 0; r2 < 4; ++r2) {
      const int row = w * 16 + lg * 4 + r2;
#pragma unroll
      for (int dc = 0; dc < 4; ++dc)
        po[row * 64 + dc * 16 + lr] = oacc[dc][r2];
      if (lr == 0) {
        pml[row * 2]     = mrun[r2];
        pml[row * 2 + 1] = lrun[r2];
      }
    }
  }
}

// ---------------- split-KV merge ---------------------------------------------
__global__ __launch_bounds__(256)
void reduce_kernel(const float* __restrict__ p, const float* __restrict__ partO,
                   const float* __restrict__ partML, float* __restrict__ out, int S) {
  const int t   = threadIdx.x;
  const int row = blockIdx.x * 16 + (t >> 4);
  const int c0  = (t & 15) * 4;
  const int qt  = row >> 6;
  const int rin = row & 63;

  float m = -1e30f;
  for (int s2 = 0; s2 < S; ++s2)
    m = fmaxf(m, partML[((size_t)(qt * S + s2)) * 128 + rin * 2]);
  float L = 0.f;
  float4 O = {0.f, 0.f, 0.f, 0.f};
  for (int s2 = 0; s2 < S; ++s2) {
    const size_t b = (size_t)(qt * S + s2);
    const float ms = partML[b * 128 + rin * 2];
    const float ls = partML[b * 128 + rin * 2 + 1];
    const float sc = exp2f(ms - m);
    L += ls * sc;
    const float4 o4 = *(const float4*)&partO[b * 4096 + rin * 64 + c0];
    O.x += o4.x * sc; O.y += o4.y * sc; O.z += o4.z * sc; O.w += o4.w * sc;
  }
  const float inv = 1.0f / L;
  const float4 pv = *(const float4*)&p[(size_t)row * DIM + c0];
  float4 r;
  r.x = pv.x + 0.1f * (O.x * inv - pv.x);
  r.y = pv.y + 0.1f * (O.y * inv - pv.y);
  r.z = pv.z + 0.1f * (O.z * inv - pv.z);
  r.w = pv.w + 0.1f * (O.w * inv - pv.w);
  *(float4*)&out[(size_t)row * DIM + c0] = r;
}

// ---------------- fallback (R1 kernel) if ws too small -----------------------
#define LDE 88
__global__ __launch_bounds__(256)
void grad_attn_fb(const float* __restrict__ p, float* __restrict__ out) {
  __shared__ __align__(16) unsigned short sKhi[BK][LDE];
  __shared__ __align__(16) unsigned short sKlo[BK][LDE];
  __shared__ __align__(16) unsigned short sVt[DIM][LDE];
  __shared__ __align__(16) unsigned short sP[4][16][LDE];
  const int t = threadIdx.x, w = t >> 6, l = t & 63, lr = l & 15, lg = l >> 4;
  const int q0 = blockIdx.x * 64 + w * 16;
  short8 qhi[2], qlo[2];
#pragma unroll
  for (int kc = 0; kc < 2; ++kc) {
    const float* qp = p + (size_t)(q0 + lr) * DIM + kc * 32 + lg * 8;
    float4 fa = *(const float4*)qp;
    float4 fb = *(const float4*)(qp + 4);
    float v[8] = {fa.x, fa.y, fa.z, fa.w, fb.x, fb.y, fb.z, fb.w};
    short8 h, lo2;
#pragma unroll
    for (int i = 0; i < 8; ++i) {
      unsigned short hb = f2bf(v[i]);
      h[i] = (short)hb;
      lo2[i] = (short)f2bf(v[i] - bf2f(hb));
    }
    qhi[kc] = h; qlo[kc] = lo2;
  }
  const f32x4 z4 = {0.f, 0.f, 0.f, 0.f};
  f32x4 oacc[4] = {z4, z4, z4, z4};
  float mrun[4] = {-1e30f, -1e30f, -1e30f, -1e30f};
  float lrun[4] = {0.f, 0.f, 0.f, 0.f};
  const int srow = (t >> 3) * 2, sc0 = (t & 7) * 8;
  const int scs = sc0 ^ (((srow >> 3) & 7) << 3);
  const float S2 = -4.0f * 1.4426950408889634f;
  for (int kt = 0; kt < NT; ++kt) {
    const int kv0 = kt * BK;
    __syncthreads();
    {
      const float* s0 = p + (size_t)(kv0 + srow) * DIM + sc0;
      float4 a0 = *(const float4*)s0;
      float4 b0 = *(const float4*)(s0 + 4);
      float4 a1 = *(const float4*)(s0 + DIM);
      float4 b1 = *(const float4*)(s0 + DIM + 4);
      float v0[8] = {a0.x, a0.y, a0.z, a0.w, b0.x, b0.y, b0.z, b0.w};
      float v1[8] = {a1.x, a1.y, a1.z, a1.w, b1.x, b1.y, b1.z, b1.w};
      short8 h0, h1, l0, l1;
#pragma unroll
      for (int i = 0; i < 8; ++i) {
        unsigned short hb0 = f2bf(v0[i]);
        unsigned short hb1 = f2bf(v1[i]);
        h0[i] = (short)hb0; l0[i] = (short)f2bf(v0[i] - bf2f(hb0));
        h1[i] = (short)hb1; l1[i] = (short)f2bf(v1[i] - bf2f(hb1));
      }
      *(short8*)&sKhi[srow][scs] = h0;
      *(short8*)&sKlo[srow][scs] = l0;
      *(short8*)&sKhi[srow + 1][scs] = h1;
      *(short8*)&sKlo[srow + 1][scs] = l1;
#pragma unroll
      for (int i = 0; i < 8; ++i) {
        int d = sc0 + i;
        unsigned pk = (unsigned)(unsigned short)h0[i] |
                      (((unsigned)(unsigned short)h1[i]) << 16);
        *(unsigned*)&sVt[d][srow ^ (((d >> 3) & 7) << 3)] = pk;
      }
    }
    __syncthreads();
    f32x4 acc[4] = {z4, z4, z4, z4};
#pragma unroll
    for (int c = 0; c < 4; ++c) {
      const int krow = c * 16 + lr;
      const int swc = ((krow >> 3) & 7) << 3;
#pragma unroll
      for (int kc = 0; kc < 2; ++kc) {
        const int off = (kc * 32 + lg * 8) ^ swc;
        short8 bh = *(const short8*)&sKhi[krow][off];
        short8 bl = *(const short8*)&sKlo[krow][off];
        acc[c] = mfma_bf16(qhi[kc], bh, acc[c]);
        acc[c] = mfma_bf16(qhi[kc], bl, acc[c]);
        acc[c] = mfma_bf16(qlo[kc], bh, acc[c]);
      }
    }
    float P[4][4];
#pragma unroll
    for (int r = 0; r < 4; ++r) {
      float e0 = acc[0][r] * S2, e1 = acc[1][r] * S2;
      float e2 = acc[2][r] * S2, e3 = acc[3][r] * S2;
      float mt = fmaxf(fmaxf(e0, e1), fmaxf(e2, e3));
      mt = fmaxf(mt, __shfl_xor(mt, 1));
      mt = fmaxf(mt, __shfl_xor(mt, 2));
      mt = fmaxf(mt, __shfl_xor(mt, 4));
      mt = fmaxf(mt, __shfl_xor(mt, 8));
      const float mn = fmaxf(mrun[r], mt);
      const float sc = exp2f(mrun[r] - mn);
      mrun[r] = mn;
      float p0 = exp2f(e0 - mn), p1 = exp2f(e1 - mn);
      float p2 = exp2f(e2 - mn), p3 = exp2f(e3 - mn);
      P[0][r] = p0; P[1][r] = p1; P[2][r] = p2; P[3][r] = p3;
      float ps = (p0 + p1) + (p2 + p3);
      ps += __shfl_xor(ps, 1);
      ps += __shfl_xor(ps, 2);
      ps += __shfl_xor(ps, 4);
      ps += __shfl_xor(ps, 8);
      lrun[r] = lrun[r] * sc + ps;
#pragma unroll
      for (int dc = 0; dc < 4; ++dc) oacc[dc][r] *= sc;
    }
    {
      const int irow = lg * 4;
      const int swp = ((l >> 5) & 1) << 3;
#pragma unroll
      for (int c = 0; c < 4; ++c) {
        const int colb = (c * 16 + lr) ^ swp;
#pragma unroll
        for (int r = 0; r < 4; ++r) sP[w][irow + r][colb] = f2bf(P[c][r]);
      }
    }
#pragma unroll
    for (int kc = 0; kc < 2; ++kc) {
      const int kb = kc * 32 + lg * 8;
      short8 pa = *(const short8*)&sP[w][lr][kb ^ (((lr >> 3) & 1) << 3)];
#pragma unroll
      for (int dc = 0; dc < 4; ++dc) {
        const int d = dc * 16 + lr;
        short8 vb = *(const short8*)&sVt[d][kb ^ (((d >> 3) & 7) << 3)];
        oacc[dc] = mfma_bf16(pa, vb, oacc[dc]);
      }
    }
  }
#pragma unroll
  for (int r = 0; r < 4; ++r) {
    const float inv = 1.0f / lrun[r];
    const size_t grow = (size_t)(q0 + lg * 4 + r) * DIM;
#pragma unroll
    for (int dc = 0; dc < 4; ++dc) {
      const int col = dc * 16 + lr;
      const float pv = p[grow + col];
      const float o = oacc[dc][r] * inv;
      out[grow + col] = pv + 0.1f * (o - pv);
    }
  }
}

extern "C" void kernel_launch(void* const* d_in, const int* in_sizes, int n_in,
                              void* d_out, int out_size, void* d_ws, size_t ws_size,
                              hipStream_t stream) {
  const float* p = (const float*)d_in[0];
  float* out = (float*)d_out;
  unsigned char* ws = (unsigned char*)d_ws;
  const size_t tiles_bytes = (size_t)NT * TILE_BYTES;  // 6 MB

  if (ws_size < tiles_bytes) {  // no workspace: fallback to R1 kernel
    grad_attn_fb<<<dim3(NQT), dim3(256), 0, stream>>>(p, out);
    return;
  }
  int S = 8;
  while (S > 1) {
    size_t need = tiles_bytes + (size_t)NQT * S * 16384 + (size_t)NQT * S * 512;
    if (need <= ws_size) break;
    S >>= 1;
  }
  float* partO  = (float*)(ws + tiles_bytes);
  float* partML = (float*)(ws + tiles_bytes + (size_t)NQT * S * 16384);

  pack_kernel<<<dim3(NT), dim3(256), 0, stream>>>(p, ws);
  attn_main<<<dim3(NQT, S), dim3(256), 0, stream>>>(p, ws, out, partO, partML, S,
                                                    S == 1 ? 1 : 0);
  if (S > 1)
    reduce_kernel<<<dim3(NROWS / 16), dim3(256), 0, stream>>>(p, partO, partML, out, S);
}

// Round 4
// 163.210 us; speedup vs baseline: 4.2906x; 2.0279x over previous
//
#include <hip/hip_runtime.h>
#include <stdint.h>

#define NROWS 16384
#define DIM 64
#define BK 64
#define NT (NROWS / BK)        // 256 KV tiles
#define NQT (NROWS / 64)       // 256 Q blocks (64 q-rows each)
#define TILE_BYTES 16384       // K f16 (8K) + Vt f16 (8K), swizzled
#define VT_OFF 8192

typedef __attribute__((ext_vector_type(8))) _Float16 f16x8;
typedef __attribute__((ext_vector_type(8))) unsigned short ushort8;
typedef __attribute__((ext_vector_type(4))) float f32x4;
typedef __attribute__((ext_vector_type(8))) __bf16 bf16x8;
typedef __attribute__((ext_vector_type(8))) short short8;

#define WAITVM0 asm volatile("s_waitcnt vmcnt(0)" ::: "memory")

static __device__ __forceinline__ f32x4 mfma_f16(f16x8 a, f16x8 b, f32x4 c) {
  return __builtin_amdgcn_mfma_f32_16x16x32_f16(a, b, c, 0, 0, 0);
}
static __device__ __forceinline__ void gload_lds16(const void* g, void* l) {
  __builtin_amdgcn_global_load_lds(
      (const __attribute__((address_space(1))) unsigned int*)(uintptr_t)g,
      (__attribute__((address_space(3))) unsigned int*)(unsigned int)(uintptr_t)l,
      16, 0, 0);
}
static __device__ __forceinline__ unsigned pk_f16(float a, float b) {
  return __builtin_bit_cast(unsigned, __builtin_amdgcn_cvt_pkrtz(a, b));
}
// bf16 helpers for fallback kernel
static __device__ __forceinline__ unsigned short f2bf(float x) {
  unsigned u = __builtin_bit_cast(unsigned, x);
  u = (u + 0x7fffu + ((u >> 16) & 1u)) >> 16;
  return (unsigned short)u;
}
static __device__ __forceinline__ float bf2f(unsigned short b) {
  return __builtin_bit_cast(float, ((unsigned)b) << 16);
}
static __device__ __forceinline__ f32x4 mfma_bf16(short8 a, short8 b, f32x4 c) {
  return __builtin_amdgcn_mfma_f32_16x16x32_bf16(
      __builtin_bit_cast(bf16x8, a), __builtin_bit_cast(bf16x8, b), c, 0, 0, 0);
}

// ---------------- prologue: pack p -> swizzled f16 tiles (K + Vt) ------------
__global__ __launch_bounds__(256)
void pack_kernel(const float* __restrict__ p, unsigned char* __restrict__ tiles) {
  __shared__ unsigned short sT[64][68];
  const int kt = blockIdx.x;
  const int t  = threadIdx.x;
  const int r  = t >> 2;
  const int q4 = t & 3;
  const int d0 = q4 * 16;

  const float* src = p + ((size_t)(kt * 64 + r)) * DIM + d0;
  float4 f0 = ((const float4*)src)[0];
  float4 f1 = ((const float4*)src)[1];
  float4 f2 = ((const float4*)src)[2];
  float4 f3 = ((const float4*)src)[3];
  float v[16] = {f0.x, f0.y, f0.z, f0.w, f1.x, f1.y, f1.z, f1.w,
                 f2.x, f2.y, f2.z, f2.w, f3.x, f3.y, f3.z, f3.w};
  ushort8 h0, h1;
#pragma unroll
  for (int i = 0; i < 8; ++i) {
    h0[i] = __builtin_bit_cast(unsigned short, (_Float16)v[i]);       // RNE
    h1[i] = __builtin_bit_cast(unsigned short, (_Float16)v[8 + i]);
  }
  unsigned char* tb = tiles + (size_t)kt * TILE_BYTES;
  const int swz = (r & 7) << 4;
  *(ushort8*)(tb + r * 128 + ((2 * d0) ^ swz))      = h0;
  *(ushort8*)(tb + r * 128 + ((2 * d0 + 16) ^ swz)) = h1;

  *(ushort8*)&sT[r][d0]     = h0;
  *(ushort8*)&sT[r][d0 + 8] = h1;
  __syncthreads();
  const int d  = t >> 2;
  const int k0 = (t & 3) * 16;
  ushort8 a8, b8;
#pragma unroll
  for (int j = 0; j < 8; ++j) {
    a8[j] = sT[k0 + j][d];
    b8[j] = sT[k0 + 8 + j][d];
  }
  const int swzd = (d & 7) << 4;
  *(ushort8*)(tb + VT_OFF + d * 128 + ((2 * k0) ^ swzd))      = a8;
  *(ushort8*)(tb + VT_OFF + d * 128 + ((2 * k0 + 16) ^ swzd)) = b8;
}

// ---------------- main flash kernel (split-KV, swapped QK^T, f16) ------------
__global__ __launch_bounds__(256)
void attn_main(const float* __restrict__ p, const unsigned char* __restrict__ tiles,
               float* __restrict__ out, float* __restrict__ partO,
               float* __restrict__ partML, int S, int writeDirect) {
  __shared__ __align__(16) unsigned char sbuf[2][TILE_BYTES];
  __shared__ __align__(16) unsigned char sPb[4][2048];

  const int t  = threadIdx.x;
  const int w  = t >> 6;
  const int l  = t & 63;
  const int lr = l & 15;
  const int lg = l >> 4;
  const int qt = blockIdx.x;
  const int s  = blockIdx.y;
  const int ntp = NT / S;
  const int kt0 = s * ntp;
  const int swz = (lr & 7) << 4;

  // Q fragments (B-operand: col=lr=q, k-dim d=lg*8+i) from packed tiles
  const unsigned char* qtb = tiles + (size_t)qt * TILE_BYTES;
  f16x8 qf[2];
#pragma unroll
  for (int kc = 0; kc < 2; ++kc)
    qf[kc] = *(const f16x8*)(qtb + (w * 16 + lr) * 128 + ((kc * 64 + lg * 16) ^ swz));

  const f32x4 z4 = {0.f, 0.f, 0.f, 0.f};
  f32x4 oacc[4] = {z4, z4, z4, z4};
  float mrun = -1e30f;     // per-lane stats for q = lr (replicated over lg)
  float lrun = 0.f;
  const float S2 = -4.0f * 1.4426950408889634f;  // log2-domain score scale

  auto STAGE = [&](int kt, int b) {
    const unsigned char* g = tiles + (size_t)kt * TILE_BYTES + (w * 4) * 1024 + l * 16;
    unsigned char* lb = &sbuf[b][(w * 4) * 1024];
#pragma unroll
    for (int c = 0; c < 4; ++c)
      gload_lds16(g + c * 1024, lb + c * 1024);
  };

  STAGE(kt0, 0);
  WAITVM0;
  __builtin_amdgcn_s_barrier();

  for (int i = 0; i < ntp; ++i) {
    if (i + 1 < ntp) STAGE(kt0 + i + 1, (i + 1) & 1);

    const unsigned char* kb = &sbuf[i & 1][0];

    // ---- QK^T swapped: S^T[k][q] = mfma(A=K, B=Q). acc[c][r]: k=c*16+lg*4+r, q=lr
    f32x4 acc[4] = {z4, z4, z4, z4};
#pragma unroll
    for (int c = 0; c < 4; ++c) {
#pragma unroll
      for (int kc = 0; kc < 2; ++kc) {
        f16x8 kf = *(const f16x8*)(kb + (c * 16 + lr) * 128 + ((kc * 64 + lg * 16) ^ swz));
        acc[c] = mfma_f16(kf, qf[kc], acc[c]);
      }
    }

    // ---- per-lane softmax for q=lr (16 scores in-lane, 2 shfls to finish)
    f32x4 v01, v23, vm;
#pragma unroll
    for (int r = 0; r < 4; ++r) {
      v01[r] = fminf(acc[0][r], acc[1][r]);
      v23[r] = fminf(acc[2][r], acc[3][r]);
      vm[r]  = fminf(v01[r], v23[r]);
    }
    float amin = fminf(fminf(vm[0], vm[1]), fminf(vm[2], vm[3]));
    amin = fminf(amin, __shfl_xor(amin, 16));
    amin = fminf(amin, __shfl_xor(amin, 32));
    const float emax = S2 * amin;        // S2 < 0: max of log2-score

    if (__any(emax > mrun + 8.0f)) {     // T13 defer-rescale
      const float mnew = fmaxf(mrun, emax);
      const float sc = exp2f(mrun - mnew);
      mrun = mnew;
      lrun *= sc;
      float scr[4];
#pragma unroll
      for (int r = 0; r < 4; ++r) scr[r] = __shfl(sc, lg * 4 + r);
#pragma unroll
      for (int dc = 0; dc < 4; ++dc)
#pragma unroll
        for (int r = 0; r < 4; ++r) oacc[dc][r] *= scr[r];
    }

    // ---- P = exp2(S2*acc - mrun), sum, convert, store to sP
    const float nm = -mrun;
    float pe[4][4];
    float lsum = 0.f;
#pragma unroll
    for (int c = 0; c < 4; ++c) {
#pragma unroll
      for (int r = 0; r < 4; ++r)
        pe[c][r] = exp2f(fmaf(acc[c][r], S2, nm));
      lsum += (pe[c][0] + pe[c][1]) + (pe[c][2] + pe[c][3]);
    }
    lsum += __shfl_xor(lsum, 16);
    lsum += __shfl_xor(lsum, 32);
    lrun += lsum;

    unsigned char* pw = &sPb[w][0];
#pragma unroll
    for (int c = 0; c < 4; ++c) {
      uint2 u;
      u.x = pk_f16(pe[c][0], pe[c][1]);
      u.y = pk_f16(pe[c][2], pe[c][3]);
      *(uint2*)(pw + lr * 128 + ((c * 32 + lg * 8) ^ swz)) = u;  // P[q=lr][k=16c+4lg..+3]
    }

    // ---- PV: O[q][d] += P * V  (A=P row=lr=q, B=Vt col=lr=d)
#pragma unroll
    for (int kc = 0; kc < 2; ++kc) {
      f16x8 pa = *(const f16x8*)(pw + lr * 128 + ((kc * 64 + lg * 16) ^ swz));
#pragma unroll
      for (int dc = 0; dc < 4; ++dc) {
        f16x8 vb = *(const f16x8*)(kb + VT_OFF + (dc * 16 + lr) * 128 +
                                   ((kc * 64 + lg * 16) ^ swz));
        oacc[dc] = mfma_f16(pa, vb, oacc[dc]);
      }
    }

    WAITVM0;                       // next tile landed (hidden under compute)
    __builtin_amdgcn_s_barrier();
  }

  // ---- epilogue. oacc row = q' = lg*4+r, col d = dc*16+lr
  if (writeDirect) {
    float lq[4];
#pragma unroll
    for (int r = 0; r < 4; ++r) lq[r] = __shfl(lrun, lg * 4 + r);
#pragma unroll
    for (int r = 0; r < 4; ++r) {
      const float inv = 1.0f / lq[r];
      const size_t grow = (size_t)(qt * 64 + w * 16 + lg * 4 + r) * DIM;
#pragma unroll
      for (int dc = 0; dc < 4; ++dc) {
        const int col = dc * 16 + lr;
        const float pv = p[grow + col];
        out[grow + col] = pv + 0.1f * (oacc[dc][r] * inv - pv);
      }
    }
  } else {
    float* po  = partO + (size_t)(qt * S + s) * 4096;
    float* pml = partML + (size_t)(qt * S + s) * 128;
#pragma unroll
    for (int r = 0; r < 4; ++r) {
      const int row = w * 16 + lg * 4 + r;
#pragma unroll
      for (int dc = 0; dc < 4; ++dc)
        po[row * 64 + dc * 16 + lr] = oacc[dc][r];
    }
    if (l < 16) {
      pml[(w * 16 + l) * 2]     = mrun;
      pml[(w * 16 + l) * 2 + 1] = lrun;
    }
  }
}

// ---------------- split-KV merge ---------------------------------------------
__global__ __launch_bounds__(256)
void reduce_kernel(const float* __restrict__ p, const float* __restrict__ partO,
                   const float* __restrict__ partML, float* __restrict__ out, int S) {
  const int t   = threadIdx.x;
  const int row = blockIdx.x * 16 + (t >> 4);
  const int c0  = (t & 15) * 4;
  const int qt  = row >> 6;
  const int rin = row & 63;

  float m = -1e30f;
  for (int s2 = 0; s2 < S; ++s2)
    m = fmaxf(m, partML[((size_t)(qt * S + s2)) * 128 + rin * 2]);
  float L = 0.f;
  float4 O = {0.f, 0.f, 0.f, 0.f};
  for (int s2 = 0; s2 < S; ++s2) {
    const size_t b = (size_t)(qt * S + s2);
    const float ms = partML[b * 128 + rin * 2];
    const float ls = partML[b * 128 + rin * 2 + 1];
    const float sc = exp2f(ms - m);
    L += ls * sc;
    const float4 o4 = *(const float4*)&partO[b * 4096 + rin * 64 + c0];
    O.x += o4.x * sc; O.y += o4.y * sc; O.z += o4.z * sc; O.w += o4.w * sc;
  }
  const float inv = 1.0f / L;
  const float4 pv = *(const float4*)&p[(size_t)row * DIM + c0];
  float4 r;
  r.x = pv.x + 0.1f * (O.x * inv - pv.x);
  r.y = pv.y + 0.1f * (O.y * inv - pv.y);
  r.z = pv.z + 0.1f * (O.z * inv - pv.z);
  r.w = pv.w + 0.1f * (O.w * inv - pv.w);
  *(float4*)&out[(size_t)row * DIM + c0] = r;
}

// ---------------- fallback (R1 kernel) if ws too small -----------------------
#define LDE 88
__global__ __launch_bounds__(256)
void grad_attn_fb(const float* __restrict__ p, float* __restrict__ out) {
  __shared__ __align__(16) unsigned short sKhi[BK][LDE];
  __shared__ __align__(16) unsigned short sKlo[BK][LDE];
  __shared__ __align__(16) unsigned short sVt[DIM][LDE];
  __shared__ __align__(16) unsigned short sP[4][16][LDE];
  const int t = threadIdx.x, w = t >> 6, l = t & 63, lr = l & 15, lg = l >> 4;
  const int q0 = blockIdx.x * 64 + w * 16;
  short8 qhi[2], qlo[2];
#pragma unroll
  for (int kc = 0; kc < 2; ++kc) {
    const float* qp = p + (size_t)(q0 + lr) * DIM + kc * 32 + lg * 8;
    float4 fa = *(const float4*)qp;
    float4 fb = *(const float4*)(qp + 4);
    float v[8] = {fa.x, fa.y, fa.z, fa.w, fb.x, fb.y, fb.z, fb.w};
    short8 h, lo2;
#pragma unroll
    for (int i = 0; i < 8; ++i) {
      unsigned short hb = f2bf(v[i]);
      h[i] = (short)hb;
      lo2[i] = (short)f2bf(v[i] - bf2f(hb));
    }
    qhi[kc] = h; qlo[kc] = lo2;
  }
  const f32x4 z4 = {0.f, 0.f, 0.f, 0.f};
  f32x4 oacc[4] = {z4, z4, z4, z4};
  float mrun[4] = {-1e30f, -1e30f, -1e30f, -1e30f};
  float lrun[4] = {0.f, 0.f, 0.f, 0.f};
  const int srow = (t >> 3) * 2, sc0 = (t & 7) * 8;
  const int scs = sc0 ^ (((srow >> 3) & 7) << 3);
  const float S2 = -4.0f * 1.4426950408889634f;
  for (int kt = 0; kt < NT; ++kt) {
    const int kv0 = kt * BK;
    __syncthreads();
    {
      const float* s0 = p + (size_t)(kv0 + srow) * DIM + sc0;
      float4 a0 = *(const float4*)s0;
      float4 b0 = *(const float4*)(s0 + 4);
      float4 a1 = *(const float4*)(s0 + DIM);
      float4 b1 = *(const float4*)(s0 + DIM + 4);
      float v0[8] = {a0.x, a0.y, a0.z, a0.w, b0.x, b0.y, b0.z, b0.w};
      float v1[8] = {a1.x, a1.y, a1.z, a1.w, b1.x, b1.y, b1.z, b1.w};
      short8 h0, h1, l0, l1;
#pragma unroll
      for (int i = 0; i < 8; ++i) {
        unsigned short hb0 = f2bf(v0[i]);
        unsigned short hb1 = f2bf(v1[i]);
        h0[i] = (short)hb0; l0[i] = (short)f2bf(v0[i] - bf2f(hb0));
        h1[i] = (short)hb1; l1[i] = (short)f2bf(v1[i] - bf2f(hb1));
      }
      *(short8*)&sKhi[srow][scs] = h0;
      *(short8*)&sKlo[srow][scs] = l0;
      *(short8*)&sKhi[srow + 1][scs] = h1;
      *(short8*)&sKlo[srow + 1][scs] = l1;
#pragma unroll
      for (int i = 0; i < 8; ++i) {
        int d = sc0 + i;
        unsigned pk = (unsigned)(unsigned short)h0[i] |
                      (((unsigned)(unsigned short)h1[i]) << 16);
        *(unsigned*)&sVt[d][srow ^ (((d >> 3) & 7) << 3)] = pk;
      }
    }
    __syncthreads();
    f32x4 acc[4] = {z4, z4, z4, z4};
#pragma unroll
    for (int c = 0; c < 4; ++c) {
      const int krow = c * 16 + lr;
      const int swc = ((krow >> 3) & 7) << 3;
#pragma unroll
      for (int kc = 0; kc < 2; ++kc) {
        const int off = (kc * 32 + lg * 8) ^ swc;
        short8 bh = *(const short8*)&sKhi[krow][off];
        short8 bl = *(const short8*)&sKlo[krow][off];
        acc[c] = mfma_bf16(qhi[kc], bh, acc[c]);
        acc[c] = mfma_bf16(qhi[kc], bl, acc[c]);
        acc[c] = mfma_bf16(qlo[kc], bh, acc[c]);
      }
    }
    float P[4][4];
#pragma unroll
    for (int r = 0; r < 4; ++r) {
      float e0 = acc[0][r] * S2, e1 = acc[1][r] * S2;
      float e2 = acc[2][r] * S2, e3 = acc[3][r] * S2;
      float mt = fmaxf(fmaxf(e0, e1), fmaxf(e2, e3));
      mt = fmaxf(mt, __shfl_xor(mt, 1));
      mt = fmaxf(mt, __shfl_xor(mt, 2));
      mt = fmaxf(mt, __shfl_xor(mt, 4));
      mt = fmaxf(mt, __shfl_xor(mt, 8));
      const float mn = fmaxf(mrun[r], mt);
      const float sc = exp2f(mrun[r] - mn);
      mrun[r] = mn;
      float p0 = exp2f(e0 - mn), p1 = exp2f(e1 - mn);
      float p2 = exp2f(e2 - mn), p3 = exp2f(e3 - mn);
      P[0][r] = p0; P[1][r] = p1; P[2][r] = p2; P[3][r] = p3;
      float ps = (p0 + p1) + (p2 + p3);
      ps += __shfl_xor(ps, 1);
      ps += __shfl_xor(ps, 2);
      ps += __shfl_xor(ps, 4);
      ps += __shfl_xor(ps, 8);
      lrun[r] = lrun[r] * sc + ps;
#pragma unroll
      for (int dc = 0; dc < 4; ++dc) oacc[dc][r] *= sc;
    }
    {
      const int irow = lg * 4;
      const int swp = ((l >> 5) & 1) << 3;
#pragma unroll
      for (int c = 0; c < 4; ++c) {
        const int colb = (c * 16 + lr) ^ swp;
#pragma unroll
        for (int r = 0; r < 4; ++r) sP[w][irow + r][colb] = f2bf(P[c][r]);
      }
    }
#pragma unroll
    for (int kc = 0; kc < 2; ++kc) {
      const int kb = kc * 32 + lg * 8;
      short8 pa = *(const short8*)&sP[w][lr][kb ^ (((lr >> 3) & 1) << 3)];
#pragma unroll
      for (int dc = 0; dc < 4; ++dc) {
        const int d = dc * 16 + lr;
        short8 vb = *(const short8*)&sVt[d][kb ^ (((d >> 3) & 7) << 3)];
        oacc[dc] = mfma_bf16(pa, vb, oacc[dc]);
      }
    }
  }
#pragma unroll
  for (int r = 0; r < 4; ++r) {
    const float inv = 1.0f / lrun[r];
    const size_t grow = (size_t)(q0 + lg * 4 + r) * DIM;
#pragma unroll
    for (int dc = 0; dc < 4; ++dc) {
      const int col = dc * 16 + lr;
      const float pv = p[grow + col];
      out[grow + col] = pv + 0.1f * (oacc[dc][r] * inv - pv);
    }
  }
}

extern "C" void kernel_launch(void* const* d_in, const int* in_sizes, int n_in,
                              void* d_out, int out_size, void* d_ws, size_t ws_size,
                              hipStream_t stream) {
  const float* p = (const float*)d_in[0];
  float* out = (float*)d_out;
  unsigned char* ws = (unsigned char*)d_ws;
  const size_t tiles_bytes = (size_t)NT * TILE_BYTES;  // 4 MB

  if (ws_size < tiles_bytes) {
    grad_attn_fb<<<dim3(NQT), dim3(256), 0, stream>>>(p, out);
    return;
  }
  int S = 8;
  while (S > 1) {
    size_t need = tiles_bytes + (size_t)NQT * S * 16384 + (size_t)NQT * S * 512;
    if (need <= ws_size) break;
    S >>= 1;
  }
  float* partO  = (float*)(ws + tiles_bytes);
  float* partML = (float*)(ws + tiles_bytes + (size_t)NQT * S * 16384);

  pack_kernel<<<dim3(NT), dim3(256), 0, stream>>>(p, ws);
  attn_main<<<dim3(NQT, S), dim3(256), 0, stream>>>(p, ws, out, partO, partML, S,
                                                    S == 1 ? 1 : 0);
  if (S > 1)
    reduce_kernel<<<dim3(NROWS / 16), dim3(256), 0, stream>>>(p, partO, partML, out, S);
}

// Round 7
// 139.031 us; speedup vs baseline: 5.0368x; 1.1739x over previous
//
#include <hip/hip_runtime.h>
#include <stdint.h>

#define NROWS 16384
#define DIM 64
#define BK 64
#define NT (NROWS / BK)        // 256 KV tiles
#define NQT (NROWS / 64)       // 256 Q blocks (64 q-rows each)
#define TILE_BYTES 16384       // K f16 (8K) + Vt f16 (8K), swizzled
#define VT_OFF 8192
#define LOG2E 1.4426950408889634f

typedef __attribute__((ext_vector_type(8))) _Float16 f16x8;
typedef __attribute__((ext_vector_type(8))) unsigned short ushort8;
typedef __attribute__((ext_vector_type(4))) float f32x4;
typedef __attribute__((ext_vector_type(8))) __bf16 bf16x8;
typedef __attribute__((ext_vector_type(8))) short short8;

static __device__ __forceinline__ f32x4 mfma_f16(f16x8 a, f16x8 b, f32x4 c) {
  return __builtin_amdgcn_mfma_f32_16x16x32_f16(a, b, c, 0, 0, 0);
}
static __device__ __forceinline__ void gload_lds16(const void* g, void* l) {
  __builtin_amdgcn_global_load_lds(
      (const __attribute__((address_space(1))) unsigned int*)(uintptr_t)g,
      (__attribute__((address_space(3))) unsigned int*)(unsigned int)(uintptr_t)l,
      16, 0, 0);
}
static __device__ __forceinline__ unsigned pk_f16(float a, float b) {
  return __builtin_bit_cast(unsigned, __builtin_amdgcn_cvt_pkrtz(a, b));
}
static __device__ __forceinline__ float fast_exp2(float x) {
  return __builtin_amdgcn_exp2f(x);   // single v_exp_f32, hazard-scheduled
}
// scalar bf16 helpers (fallback kernel only)
static __device__ __forceinline__ unsigned short f2bf(float x) {
  unsigned u = __builtin_bit_cast(unsigned, x);
  u = (u + 0x7fffu + ((u >> 16) & 1u)) >> 16;
  return (unsigned short)u;
}
static __device__ __forceinline__ float bf2f(unsigned short b) {
  return __builtin_bit_cast(float, ((unsigned)b) << 16);
}
static __device__ __forceinline__ f32x4 mfma_bf16(short8 a, short8 b, f32x4 c) {
  return __builtin_amdgcn_mfma_f32_16x16x32_bf16(
      __builtin_bit_cast(bf16x8, a), __builtin_bit_cast(bf16x8, b), c, 0, 0, 0);
}

// ---------------- prologue: pack p -> swizzled f16 tiles (K + Vt) ------------
__global__ __launch_bounds__(256)
void pack_kernel(const float* __restrict__ p, unsigned char* __restrict__ tiles) {
  __shared__ unsigned short sT[64][68];
  const int kt = blockIdx.x;
  const int t  = threadIdx.x;
  const int r  = t >> 2;
  const int q4 = t & 3;
  const int d0 = q4 * 16;

  const float* src = p + ((size_t)(kt * 64 + r)) * DIM + d0;
  float4 f0 = ((const float4*)src)[0];
  float4 f1 = ((const float4*)src)[1];
  float4 f2 = ((const float4*)src)[2];
  float4 f3 = ((const float4*)src)[3];
  float v[16] = {f0.x, f0.y, f0.z, f0.w, f1.x, f1.y, f1.z, f1.w,
                 f2.x, f2.y, f2.z, f2.w, f3.x, f3.y, f3.z, f3.w};
  ushort8 h0, h1;
#pragma unroll
  for (int i = 0; i < 8; ++i) {
    h0[i] = __builtin_bit_cast(unsigned short, (_Float16)v[i]);       // RNE
    h1[i] = __builtin_bit_cast(unsigned short, (_Float16)v[8 + i]);
  }
  unsigned char* tb = tiles + (size_t)kt * TILE_BYTES;
  const int swz = (r & 7) << 4;
  *(ushort8*)(tb + r * 128 + ((2 * d0) ^ swz))      = h0;
  *(ushort8*)(tb + r * 128 + ((2 * d0 + 16) ^ swz)) = h1;

  *(ushort8*)&sT[r][d0]     = h0;
  *(ushort8*)&sT[r][d0 + 8] = h1;
  __syncthreads();
  const int d  = t >> 2;
  const int k0 = (t & 3) * 16;
  ushort8 a8, b8;
#pragma unroll
  for (int j = 0; j < 8; ++j) {
    a8[j] = sT[k0 + j][d];
    b8[j] = sT[k0 + 8 + j][d];
  }
  const int swzd = (d & 7) << 4;
  *(ushort8*)(tb + VT_OFF + d * 128 + ((2 * k0) ^ swzd))      = a8;
  *(ushort8*)(tb + VT_OFF + d * 128 + ((2 * k0 + 16) ^ swzd)) = b8;
}

// ---------------- main flash kernel (split-KV, swapped QK^T, f16) ------------
__global__ __launch_bounds__(256)
void attn_main(const float* __restrict__ p, const unsigned char* __restrict__ tiles,
               float* __restrict__ out, float* __restrict__ partO,
               float* __restrict__ partML, int S, int writeDirect) {
  __shared__ __align__(16) unsigned char sbuf[2][TILE_BYTES];
  __shared__ __align__(16) unsigned char sPb[4][2048];

  const int t  = threadIdx.x;
  const int w  = t >> 6;
  const int l  = t & 63;
  const int lr = l & 15;
  const int lg = l >> 4;
  const int qt = blockIdx.x;
  const int s  = blockIdx.y;
  const int ntp = NT / S;
  const int kt0 = s * ntp;
  const int swz = (lr & 7) << 4;

  // Q fragments (B-operand: col=lr=q, k-dim d=lg*8+i) from packed tiles
  const unsigned char* qtb = tiles + (size_t)qt * TILE_BYTES;
  f16x8 qf[2];
#pragma unroll
  for (int kc = 0; kc < 2; ++kc)
    qf[kc] = *(const f16x8*)(qtb + (w * 16 + lr) * 128 + ((kc * 64 + lg * 16) ^ swz));

  const f32x4 z4 = {0.f, 0.f, 0.f, 0.f};
  f32x4 oacc[4] = {z4, z4, z4, z4};
  float mrun = -1e30f;     // per-lane stats for q = lr (replicated over lg)
  float lrun = 0.f;
  const float S2 = -4.0f * LOG2E;  // log2-domain score scale

  auto STAGE = [&](int kt, int b) {
    const unsigned char* g = tiles + (size_t)kt * TILE_BYTES + (w * 4) * 1024 + l * 16;
    unsigned char* lb = &sbuf[b][(w * 4) * 1024];   // wave-uniform LDS base
#pragma unroll
    for (int c = 0; c < 4; ++c)
      gload_lds16(g + c * 1024, lb + c * 1024);
  };

  STAGE(kt0, 0);
  __syncthreads();

  for (int i = 0; i < ntp; ++i) {
    if (i + 1 < ntp) STAGE(kt0 + i + 1, (i + 1) & 1);

    const unsigned char* kb = &sbuf[i & 1][0];

    // ---- QK^T swapped: S^T[k][q] = mfma(A=K, B=Q). acc[c][r]: k=c*16+lg*4+r, q=lr
    f32x4 acc[4] = {z4, z4, z4, z4};
#pragma unroll
    for (int c = 0; c < 4; ++c) {
#pragma unroll
      for (int kc = 0; kc < 2; ++kc) {
        f16x8 kf = *(const f16x8*)(kb + (c * 16 + lr) * 128 + ((kc * 64 + lg * 16) ^ swz));
        acc[c] = mfma_f16(kf, qf[kc], acc[c]);
      }
    }

    // ---- per-lane softmax for q=lr (16 scores in-lane, 2 shfls to finish)
    f32x4 v01, v23, vm;
#pragma unroll
    for (int r = 0; r < 4; ++r) {
      v01[r] = fminf(acc[0][r], acc[1][r]);
      v23[r] = fminf(acc[2][r], acc[3][r]);
      vm[r]  = fminf(v01[r], v23[r]);
    }
    float amin = fminf(fminf(vm[0], vm[1]), fminf(vm[2], vm[3]));
    amin = fminf(amin, __shfl_xor(amin, 16));
    amin = fminf(amin, __shfl_xor(amin, 32));
    const float emax = S2 * amin;        // S2 < 0: max of log2-score

    if (__any(emax > mrun + 8.0f)) {     // T13 defer-rescale
      const float mnew = fmaxf(mrun, emax);
      const float sc = fast_exp2(mrun - mnew);
      mrun = mnew;
      lrun *= sc;
      float scr[4];
#pragma unroll
      for (int r = 0; r < 4; ++r) scr[r] = __shfl(sc, lg * 4 + r);
#pragma unroll
      for (int dc = 0; dc < 4; ++dc)
#pragma unroll
        for (int r = 0; r < 4; ++r) oacc[dc][r] *= scr[r];
    }

    // ---- P = 2^(S2*dot - mrun), sum, convert, store to sP
    const float nm = -mrun;
    float pe[4][4];
    float lsum = 0.f;
#pragma unroll
    for (int c = 0; c < 4; ++c) {
#pragma unroll
      for (int r = 0; r < 4; ++r)
        pe[c][r] = fast_exp2(fmaf(acc[c][r], S2, nm));
      lsum += (pe[c][0] + pe[c][1]) + (pe[c][2] + pe[c][3]);
    }
    lsum += __shfl_xor(lsum, 16);
    lsum += __shfl_xor(lsum, 32);
    lrun += lsum;

    unsigned char* pw = &sPb[w][0];
#pragma unroll
    for (int c = 0; c < 4; ++c) {
      uint2 u;
      u.x = pk_f16(pe[c][0], pe[c][1]);
      u.y = pk_f16(pe[c][2], pe[c][3]);
      *(uint2*)(pw + lr * 128 + ((c * 32 + lg * 8) ^ swz)) = u;  // P[q=lr][k=16c+4lg..+3]
    }

    // ---- PV: O[q][d] += P * V  (A=P row=lr=q, B=Vt col=lr=d)
#pragma unroll
    for (int kc = 0; kc < 2; ++kc) {
      f16x8 pa = *(const f16x8*)(pw + lr * 128 + ((kc * 64 + lg * 16) ^ swz));
#pragma unroll
      for (int dc = 0; dc < 4; ++dc) {
        f16x8 vb = *(const f16x8*)(kb + VT_OFF + (dc * 16 + lr) * 128 +
                                   ((kc * 64 + lg * 16) ^ swz));
        oacc[dc] = mfma_f16(pa, vb, oacc[dc]);
      }
    }

    __syncthreads();   // full drain (vmcnt incl. staged loads) + barrier, ordered
  }

  // ---- epilogue. oacc row = q' = lg*4+r, col d = dc*16+lr
  if (writeDirect) {
    float lq[4];
#pragma unroll
    for (int r = 0; r < 4; ++r) lq[r] = __shfl(lrun, lg * 4 + r);
#pragma unroll
    for (int r = 0; r < 4; ++r) {
      const float inv = 1.0f / lq[r];
      const size_t grow = (size_t)(qt * 64 + w * 16 + lg * 4 + r) * DIM;
#pragma unroll
      for (int dc = 0; dc < 4; ++dc) {
        const int col = dc * 16 + lr;
        const float pv = p[grow + col];
        out[grow + col] = pv + 0.1f * (oacc[dc][r] * inv - pv);
      }
    }
  } else {
    float* po  = partO + (size_t)(qt * S + s) * 4096;
    float* pml = partML + (size_t)(qt * S + s) * 128;
#pragma unroll
    for (int r = 0; r < 4; ++r) {
      const int row = w * 16 + lg * 4 + r;
#pragma unroll
      for (int dc = 0; dc < 4; ++dc)
        po[row * 64 + dc * 16 + lr] = oacc[dc][r];
    }
    if (l < 16) {
      pml[(w * 16 + l) * 2]     = mrun;
      pml[(w * 16 + l) * 2 + 1] = lrun;
    }
  }
}

// ---------------- split-KV merge ---------------------------------------------
__global__ __launch_bounds__(256)
void reduce_kernel(const float* __restrict__ p, const float* __restrict__ partO,
                   const float* __restrict__ partML, float* __restrict__ out, int S) {
  const int t   = threadIdx.x;
  const int row = blockIdx.x * 16 + (t >> 4);
  const int c0  = (t & 15) * 4;
  const int qt  = row >> 6;
  const int rin = row & 63;

  float m = -1e30f;
  for (int s2 = 0; s2 < S; ++s2)
    m = fmaxf(m, partML[((size_t)(qt * S + s2)) * 128 + rin * 2]);
  float L = 0.f;
  float4 O = {0.f, 0.f, 0.f, 0.f};
  for (int s2 = 0; s2 < S; ++s2) {
    const size_t b = (size_t)(qt * S + s2);
    const float ms = partML[b * 128 + rin * 2];
    const float ls = partML[b * 128 + rin * 2 + 1];
    const float sc = exp2f(ms - m);
    L += ls * sc;
    const float4 o4 = *(const float4*)&partO[b * 4096 + rin * 64 + c0];
    O.x += o4.x * sc; O.y += o4.y * sc; O.z += o4.z * sc; O.w += o4.w * sc;
  }
  const float inv = 1.0f / L;
  const float4 pv = *(const float4*)&p[(size_t)row * DIM + c0];
  float4 r;
  r.x = pv.x + 0.1f * (O.x * inv - pv.x);
  r.y = pv.y + 0.1f * (O.y * inv - pv.y);
  r.z = pv.z + 0.1f * (O.z * inv - pv.z);
  r.w = pv.w + 0.1f * (O.w * inv - pv.w);
  *(float4*)&out[(size_t)row * DIM + c0] = r;
}

// ---------------- fallback (R1 kernel) if ws too small -----------------------
#define LDE 88
__global__ __launch_bounds__(256)
void grad_attn_fb(const float* __restrict__ p, float* __restrict__ out) {
  __shared__ __align__(16) unsigned short sKhi[BK][LDE];
  __shared__ __align__(16) unsigned short sKlo[BK][LDE];
  __shared__ __align__(16) unsigned short sVt[DIM][LDE];
  __shared__ __align__(16) unsigned short sP[4][16][LDE];
  const int t = threadIdx.x, w = t >> 6, l = t & 63, lr = l & 15, lg = l >> 4;
  const int q0 = blockIdx.x * 64 + w * 16;
  short8 qhi[2], qlo[2];
#pragma unroll
  for (int kc = 0; kc < 2; ++kc) {
    const float* qp = p + (size_t)(q0 + lr) * DIM + kc * 32 + lg * 8;
    float4 fa = *(const float4*)qp;
    float4 fb = *(const float4*)(qp + 4);
    float v[8] = {fa.x, fa.y, fa.z, fa.w, fb.x, fb.y, fb.z, fb.w};
    short8 h, lo2;
#pragma unroll
    for (int i = 0; i < 8; ++i) {
      unsigned short hb = f2bf(v[i]);
      h[i] = (short)hb;
      lo2[i] = (short)f2bf(v[i] - bf2f(hb));
    }
    qhi[kc] = h; qlo[kc] = lo2;
  }
  const f32x4 z4 = {0.f, 0.f, 0.f, 0.f};
  f32x4 oacc[4] = {z4, z4, z4, z4};
  float mrun[4] = {-1e30f, -1e30f, -1e30f, -1e30f};
  float lrun[4] = {0.f, 0.f, 0.f, 0.f};
  const int srow = (t >> 3) * 2, sc0 = (t & 7) * 8;
  const int scs = sc0 ^ (((srow >> 3) & 7) << 3);
  const float S2 = -4.0f * LOG2E;
  for (int kt = 0; kt < NT; ++kt) {
    const int kv0 = kt * BK;
    __syncthreads();
    {
      const float* s0 = p + (size_t)(kv0 + srow) * DIM + sc0;
      float4 a0 = *(const float4*)s0;
      float4 b0 = *(const float4*)(s0 + 4);
      float4 a1 = *(const float4*)(s0 + DIM);
      float4 b1 = *(const float4*)(s0 + DIM + 4);
      float v0[8] = {a0.x, a0.y, a0.z, a0.w, b0.x, b0.y, b0.z, b0.w};
      float v1[8] = {a1.x, a1.y, a1.z, a1.w, b1.x, b1.y, b1.z, b1.w};
      short8 h0, h1, l0, l1;
#pragma unroll
      for (int i = 0; i < 8; ++i) {
        unsigned short hb0 = f2bf(v0[i]);
        unsigned short hb1 = f2bf(v1[i]);
        h0[i] = (short)hb0; l0[i] = (short)f2bf(v0[i] - bf2f(hb0));
        h1[i] = (short)hb1; l1[i] = (short)f2bf(v1[i] - bf2f(hb1));
      }
      *(short8*)&sKhi[srow][scs] = h0;
      *(short8*)&sKlo[srow][scs] = l0;
      *(short8*)&sKhi[srow + 1][scs] = h1;
      *(short8*)&sKlo[srow + 1][scs] = l1;
#pragma unroll
      for (int i = 0; i < 8; ++i) {
        int d = sc0 + i;
        unsigned pk = (unsigned)(unsigned short)h0[i] |
                      (((unsigned)(unsigned short)h1[i]) << 16);
        *(unsigned*)&sVt[d][srow ^ (((d >> 3) & 7) << 3)] = pk;
      }
    }
    __syncthreads();
    f32x4 acc[4] = {z4, z4, z4, z4};
#pragma unroll
    for (int c = 0; c < 4; ++c) {
      const int krow = c * 16 + lr;
      const int swc = ((krow >> 3) & 7) << 3;
#pragma unroll
      for (int kc = 0; kc < 2; ++kc) {
        const int off = (kc * 32 + lg * 8) ^ swc;
        short8 bh = *(const short8*)&sKhi[krow][off];
        short8 bl = *(const short8*)&sKlo[krow][off];
        acc[c] = mfma_bf16(qhi[kc], bh, acc[c]);
        acc[c] = mfma_bf16(qhi[kc], bl, acc[c]);
        acc[c] = mfma_bf16(qlo[kc], bh, acc[c]);
      }
    }
    float P[4][4];
#pragma unroll
    for (int r = 0; r < 4; ++r) {
      float e0 = acc[0][r] * S2, e1 = acc[1][r] * S2;
      float e2 = acc[2][r] * S2, e3 = acc[3][r] * S2;
      float mt = fmaxf(fmaxf(e0, e1), fmaxf(e2, e3));
      mt = fmaxf(mt, __shfl_xor(mt, 1));
      mt = fmaxf(mt, __shfl_xor(mt, 2));
      mt = fmaxf(mt, __shfl_xor(mt, 4));
      mt = fmaxf(mt, __shfl_xor(mt, 8));
      const float mn = fmaxf(mrun[r], mt);
      const float sc = exp2f(mrun[r] - mn);
      mrun[r] = mn;
      float p0 = exp2f(e0 - mn), p1 = exp2f(e1 - mn);
      float p2 = exp2f(e2 - mn), p3 = exp2f(e3 - mn);
      P[0][r] = p0; P[1][r] = p1; P[2][r] = p2; P[3][r] = p3;
      float ps = (p0 + p1) + (p2 + p3);
      ps += __shfl_xor(ps, 1);
      ps += __shfl_xor(ps, 2);
      ps += __shfl_xor(ps, 4);
      ps += __shfl_xor(ps, 8);
      lrun[r] = lrun[r] * sc + ps;
#pragma unroll
      for (int dc = 0; dc < 4; ++dc) oacc[dc][r] *= sc;
    }
    {
      const int irow = lg * 4;
      const int swp = ((l >> 5) & 1) << 3;
#pragma unroll
      for (int c = 0; c < 4; ++c) {
        const int colb = (c * 16 + lr) ^ swp;
#pragma unroll
        for (int r = 0; r < 4; ++r) sP[w][irow + r][colb] = f2bf(P[c][r]);
      }
    }
#pragma unroll
    for (int kc = 0; kc < 2; ++kc) {
      const int kb = kc * 32 + lg * 8;
      short8 pa = *(const short8*)&sP[w][lr][kb ^ (((lr >> 3) & 1) << 3)];
#pragma unroll
      for (int dc = 0; dc < 4; ++dc) {
        const int d = dc * 16 + lr;
        short8 vb = *(const short8*)&sVt[d][kb ^ (((d >> 3) & 7) << 3)];
        oacc[dc] = mfma_bf16(pa, vb, oacc[dc]);
      }
    }
  }
#pragma unroll
  for (int r = 0; r < 4; ++r) {
    const float inv = 1.0f / lrun[r];
    const size_t grow = (size_t)(q0 + lg * 4 + r) * DIM;
#pragma unroll
    for (int dc = 0; dc < 4; ++dc) {
      const int col = dc * 16 + lr;
      const float pv = p[grow + col];
      out[grow + col] = pv + 0.1f * (oacc[dc][r] * inv - pv);
    }
  }
}

extern "C" void kernel_launch(void* const* d_in, const int* in_sizes, int n_in,
                              void* d_out, int out_size, void* d_ws, size_t ws_size,
                              hipStream_t stream) {
  const float* p = (const float*)d_in[0];
  float* out = (float*)d_out;
  unsigned char* ws = (unsigned char*)d_ws;
  const size_t tiles_bytes = (size_t)NT * TILE_BYTES;  // 4 MB

  if (ws_size < tiles_bytes) {
    grad_attn_fb<<<dim3(NQT), dim3(256), 0, stream>>>(p, out);
    return;
  }
  int S = 8;
  while (S > 1) {
    size_t need = tiles_bytes + (size_t)NQT * S * 16384 + (size_t)NQT * S * 512;
    if (need <= ws_size) break;
    S >>= 1;
  }
  float* partO  = (float*)(ws + tiles_bytes);
  float* partML = (float*)(ws + tiles_bytes + (size_t)NQT * S * 16384);

  pack_kernel<<<dim3(NT), dim3(256), 0, stream>>>(p, ws);
  attn_main<<<dim3(NQT, S), dim3(256), 0, stream>>>(p, ws, out, partO, partML, S,
                                                    S == 1 ? 1 : 0);
  if (S > 1)
    reduce_kernel<<<dim3(NROWS / 16), dim3(256), 0, stream>>>(p, partO, partML, out, S);
}